// Round 10
// baseline (263.046 us; speedup 1.0000x reference)
//
#include <hip/hip_runtime.h>
#include <hip/hip_fp16.h>

#define NF 64
#define KEXP 50
#define TBL 2048
#define CUTF 5.0f
#define LOG2C 0.6931471805599453f
#define GRP 64              // nodes per group (agg block granule)
#define NSC 128             // superchunks (sort blocks)
#define GMAX 2048           // max node-groups (LDS histogram bound)
#define SCAP 1536           // max records per group in agg (mean 1024, +16 sigma)

typedef unsigned long long ull;

__device__ __forceinline__ float sspf(float x) {
    return fmaxf(x, 0.0f) + log1pf(expf(-fabsf(x))) - LOG2C;
}

__device__ __forceinline__ float bcast(float v, int k) {
    return __int_as_float(__builtin_amdgcn_readlane(__float_as_int(v), k));
}

// ---------------------------------------------------------------------------
// lerp table as float2: tab2f[t][f] = ( f_t[f], (f_{t+1}[f]-f_t[f]) / 256 )
// (computes f(t) and f(t+1) in-block; exact, no cross-block dependency)
// ---------------------------------------------------------------------------
__global__ void build_tab2f_k(const float* __restrict__ f_w1, const float* __restrict__ f_b1,
                              const float* __restrict__ f_w2, const float* __restrict__ f_b2,
                              float2* __restrict__ tab2f) {
    __shared__ float rbf_s[KEXP];
    __shared__ float s_s[NF];
    const int t = blockIdx.x;
    const int f = threadIdx.x; // 0..63
    const float delta = CUTF / (float)(KEXP - 1);
    const float coeff = -0.5f / (delta * delta);
    const float dstep = CUTF / (float)(TBL - 1);
    float vals[2];
    for (int p = 0; p < 2; ++p) {
        const int tt = min(t + p, TBL - 1);
        const float d = (float)tt * dstep;
        __syncthreads();
        if (f < KEXP) {
            float dd = d - (float)f * delta;
            rbf_s[f] = expf(coeff * dd * dd);
        }
        __syncthreads();
        float t1 = f_b1[f];
        for (int k = 0; k < KEXP; ++k) t1 = fmaf(rbf_s[k], f_w1[f * KEXP + k], t1);
        __syncthreads();
        s_s[f] = sspf(t1);
        __syncthreads();
        float t2 = f_b2[f];
        for (int k = 0; k < NF; ++k) t2 = fmaf(s_s[k], f_w2[f * NF + k], t2);
        vals[p] = t2;
    }
    tab2f[(size_t)t * NF + f] = make_float2(vals[0], (vals[1] - vals[0]) * (1.0f / 256.0f));
}

// ---------------------------------------------------------------------------
// prep: h16 = fp16(x @ lin_w.T + lin_b)  (wave/node, weights in VGPR)
// ---------------------------------------------------------------------------
__global__ void __launch_bounds__(256) prep_k(
    const float* __restrict__ x, const float* __restrict__ w, const float* __restrict__ b,
    __half* __restrict__ h16, int n_nodes)
{
    const int tid = threadIdx.x;
    const int lane = tid & 63;
    float wreg[NF];
    #pragma unroll
    for (int k = 0; k < NF; k += 4) {
        float4 q = *(const float4*)(w + (size_t)lane * NF + k);
        wreg[k] = q.x; wreg[k + 1] = q.y; wreg[k + 2] = q.z; wreg[k + 3] = q.w;
    }
    const float bias = b[lane];
    const int nwaves = (gridDim.x * blockDim.x) >> 6;
    const int gw = (blockIdx.x * blockDim.x + tid) >> 6;
    for (int n = gw; n < n_nodes; n += nwaves) {
        const float xv = x[(size_t)n * NF + lane];
        float a0 = bias, a1 = 0.f, a2 = 0.f, a3 = 0.f;
        #pragma unroll
        for (int k = 0; k < NF; k += 4) {
            a0 = fmaf(bcast(xv, k),     wreg[k],     a0);
            a1 = fmaf(bcast(xv, k + 1), wreg[k + 1], a1);
            a2 = fmaf(bcast(xv, k + 2), wreg[k + 2], a2);
            a3 = fmaf(bcast(xv, k + 3), wreg[k + 3], a3);
        }
        h16[(size_t)n * NF + lane] = __float2half((a0 + a1) + (a2 + a3));
    }
}

// ---------------------------------------------------------------------------
// hist: per superchunk, RAW histogram of dst-groups -> cnt[c][g] (coalesced)
// ---------------------------------------------------------------------------
__global__ void __launch_bounds__(1024) hist_k(const int* __restrict__ nbr_dst,
                                               int n_edges, int ngroups, int chk,
                                               unsigned* __restrict__ cnt) {
    __shared__ unsigned cnt_s[GMAX];
    const int tid = threadIdx.x;
    const int c = blockIdx.x;
    const int e0 = c * chk;
    const int e1 = min(e0 + chk, n_edges);
    const int m = max(e1 - e0, 0);
    for (int g = tid; g < ngroups; g += 1024) cnt_s[g] = 0u;
    __syncthreads();
    for (int i = tid; i < m; i += 1024)
        atomicAdd(&cnt_s[(unsigned)nbr_dst[e0 + i] >> 6], 1u);
    __syncthreads();
    const size_t ob = (size_t)c * ngroups;
    for (int g = tid; g < ngroups; g += 1024) cnt[ob + g] = cnt_s[g];
}

// ---------------------------------------------------------------------------
// colscan: per group g, exclusive scan of cnt[c][g] along c -> colpre[c][g],
// and per-group total -> tot[g]. One wave, 2 chunks per lane.
// ---------------------------------------------------------------------------
__global__ void __launch_bounds__(64) colscan_k(const unsigned* __restrict__ cnt,
                                                unsigned* __restrict__ colpre,
                                                unsigned* __restrict__ tot, int ngroups) {
    const int g = blockIdx.x;
    const int lane = threadIdx.x;
    const unsigned a = cnt[(size_t)(2 * lane) * ngroups + g];
    const unsigned b = cnt[(size_t)(2 * lane + 1) * ngroups + g];
    const unsigned s = a + b;
    unsigned run = s;
    #pragma unroll
    for (int d = 1; d < 64; d <<= 1) {
        const unsigned t = __shfl_up(run, d, 64);
        if (lane >= d) run += t;
    }
    const unsigned pre = run - s;
    colpre[(size_t)(2 * lane) * ngroups + g] = pre;
    colpre[(size_t)(2 * lane + 1) * ngroups + g] = pre + a;
    if (lane == 63) tot[g] = run;
}

// ---------------------------------------------------------------------------
// base: exclusive scan over group totals -> gbase[0..ngroups]
// ---------------------------------------------------------------------------
__global__ void __launch_bounds__(64) base_k(const unsigned* __restrict__ tot,
                                             unsigned* __restrict__ gbase, int ngroups) {
    const int lane = threadIdx.x;
    unsigned carry = 0u;
    for (int base = 0; base < ngroups; base += 64) {
        const int g = base + lane;
        const unsigned v = (g < ngroups) ? tot[g] : 0u;
        unsigned run = v;
        #pragma unroll
        for (int d = 1; d < 64; d <<= 1) {
            const unsigned t = __shfl_up(run, d, 64);
            if (lane >= d) run += t;
        }
        if (g < ngroups) gbase[g] = carry + run - v;
        carry += (unsigned)__shfl((int)run, 63, 64);
    }
    if (lane == 0) gbase[ngroups] = carry;
}

// ---------------------------------------------------------------------------
// scatter2: write records to FINAL globally-sorted-by-group positions.
// rec: lo = (i0<<9)|fr8  (taboff bytes = lo & ~511, float2 row = 512B)
//      hi = (src<<7)|dstrow (hoff bytes = hi & ~127)
// ---------------------------------------------------------------------------
__global__ void __launch_bounds__(1024) scatter2_k(const int* __restrict__ nbr,
                                                   const float* __restrict__ dist,
                                                   int n_edges, int ngroups, int chk,
                                                   const unsigned* __restrict__ colpre,
                                                   const unsigned* __restrict__ gbase,
                                                   ull* __restrict__ payload) {
    __shared__ unsigned cur_s[GMAX];
    const int tid = threadIdx.x;
    const int c = blockIdx.x;
    const int e0 = c * chk;
    const int e1 = min(e0 + chk, n_edges);
    const int m = max(e1 - e0, 0);
    const size_t ob = (size_t)c * ngroups;
    for (int g = tid; g < ngroups; g += 1024) cur_s[g] = gbase[g] + colpre[ob + g];
    __syncthreads();
    const float scale = (float)(TBL - 1) / CUTF;
    for (int i = tid; i < m; i += 1024) {
        const int e = e0 + i;
        const unsigned dst = (unsigned)nbr[n_edges + e];
        const unsigned src = (unsigned)nbr[e];
        const float xx = dist[e] * scale;
        int i0 = (int)xx;
        i0 = max(0, min(i0, TBL - 2));
        const float fr = xx - (float)i0;
        const unsigned fr8 = min((unsigned)(fr * 256.0f), 255u);
        const ull rec = (ull)(((unsigned)i0 << 9) | fr8) |
                        ((ull)((src << 7) | (dst & 63u)) << 32);
        const unsigned pos = atomicAdd(&cur_s[dst >> 6], 1u);
        payload[pos] = rec;
    }
}

// ---------------------------------------------------------------------------
// agg: block = 64-node group; contiguous coalesced payload stream; in-LDS
// row-sort; pure gather-accumulate with precoded byte offsets (no atomics).
// ---------------------------------------------------------------------------
__global__ void __launch_bounds__(256) agg_k(
    const ull* __restrict__ payload, const unsigned* __restrict__ gbase,
    const __half* __restrict__ h16, const float2* __restrict__ tab2f,
    float* __restrict__ agg, int n_nodes)
{
    __shared__ ull sorted_s[SCAP];
    __shared__ unsigned cnt_s[GRP];
    __shared__ unsigned base_s[GRP];
    __shared__ unsigned cur_s[GRP];
    const int tid = threadIdx.x;
    const int lane = tid & 63;
    const int wid = tid >> 6;   // 0..3
    const int g = blockIdx.x;
    const unsigned beg = gbase[g];
    const unsigned end = gbase[g + 1];
    const unsigned tot = min(end - beg, (unsigned)SCAP);

    if (tid < GRP) cnt_s[tid] = 0u;
    __syncthreads();
    // count rows (coalesced stream)
    for (unsigned i = tid; i < tot; i += 256u) {
        const ull r = payload[beg + i];
        atomicAdd(&cnt_s[(unsigned)(r >> 32) & 63u], 1u);
    }
    __syncthreads();
    // exclusive scan over 64 row counts
    if (tid < GRP) {
        const unsigned c = cnt_s[tid];
        unsigned run = c;
        #pragma unroll
        for (int d = 1; d < 64; d <<= 1) {
            const unsigned t = __shfl_up(run, d, 64);
            if (tid >= d) run += t;
        }
        base_s[tid] = run - c;
        cur_s[tid]  = run - c;
    }
    __syncthreads();
    // place by row (stream is L2-hot on second pass)
    for (unsigned i = tid; i < tot; i += 256u) {
        const ull r = payload[beg + i];
        const unsigned pos = atomicAdd(&cur_s[(unsigned)(r >> 32) & 63u], 1u);
        sorted_s[pos] = r;
    }
    __syncthreads();
    // gather-accumulate; one coalesced store per row
    const char* tabB = (const char*)tab2f + (lane << 3);
    const char* hB   = (const char*)h16 + (lane << 1);
    auto ev = [&](ull rec) -> float {
        const unsigned lo = (unsigned)rec;
        const unsigned hi = (unsigned)(rec >> 32);
        const float2 t = *(const float2*)(tabB + (lo & 0xFFFFFE00u));
        const float hv = __half2float(*(const __half*)(hB + (hi & 0xFFFFFF80u)));
        const float filt = fmaf((float)(lo & 255u), t.y, t.x);
        return hv * filt;
    };
    const int n0 = g * GRP;
    for (int rr = 0; rr < 16; ++rr) {
        const int r = (wid << 4) + rr;
        unsigned i = base_s[r];
        const unsigned e = cur_s[r];
        float acc0 = 0.f, acc1 = 0.f;
        for (; i + 4u <= e; i += 4u) {
            const ull r0 = sorted_s[i];
            const ull r1 = sorted_s[i + 1];
            const ull r2 = sorted_s[i + 2];
            const ull r3 = sorted_s[i + 3];
            acc0 += ev(r0) + ev(r1);
            acc1 += ev(r2) + ev(r3);
        }
        for (; i < e; ++i) acc0 += ev(sorted_s[i]);
        const int n = n0 + r;
        if (n < n_nodes) agg[(size_t)n * NF + lane] = acc0 + acc1;
    }
}

// ---------------------------------------------------------------------------
// overflow fixup: groups with >SCAP records process the tail directly from
// the sorted payload with global atomics (normally zero work)
// ---------------------------------------------------------------------------
__global__ void __launch_bounds__(64) oflow2_k(const ull* __restrict__ payload,
                                               const unsigned* __restrict__ gbase,
                                               const __half* __restrict__ h16,
                                               const float2* __restrict__ tab2f,
                                               float* __restrict__ agg) {
    const int g = blockIdx.x;
    const unsigned beg = gbase[g];
    const unsigned end = gbase[g + 1];
    if (end - beg <= (unsigned)SCAP) return;
    const int lane = threadIdx.x;
    const char* tabB = (const char*)tab2f + (lane << 3);
    const char* hB   = (const char*)h16 + (lane << 1);
    for (unsigned i = beg + SCAP; i < end; ++i) {
        const ull rec = payload[i];
        const unsigned lo = (unsigned)rec;
        const unsigned hi = (unsigned)(rec >> 32);
        const float2 t = *(const float2*)(tabB + (lo & 0xFFFFFE00u));
        const float hv = __half2float(*(const __half*)(hB + (hi & 0xFFFFFF80u)));
        const float filt = fmaf((float)(lo & 255u), t.y, t.x);
        const unsigned row = (unsigned)g * GRP + (hi & 63u);
        atomicAdd(agg + (size_t)row * NF + lane, hv * filt);
    }
}

// ---------------------------------------------------------------------------
// fallback edge kernel (direct atomic scatter-add) — used only if ws too small
// ---------------------------------------------------------------------------
__global__ void edge_k(const int* __restrict__ nbr, const float* __restrict__ dist,
                       const __half* __restrict__ h16, const float2* __restrict__ tab2f,
                       float* __restrict__ agg, int n_edges) {
    const int tid = threadIdx.x;
    const int lane = tid & 63;
    const int nwaves = (gridDim.x * blockDim.x) >> 6;
    const int gw = (blockIdx.x * blockDim.x + tid) >> 6;
    const float scale = (float)(TBL - 1) / CUTF;
    const int nbatch = n_edges >> 6;
    for (int bb = gw; bb < nbatch; bb += nwaves) {
        const int e0 = bb << 6;
        int src = nbr[e0 + lane];
        int dst = nbr[n_edges + e0 + lane];
        float d = dist[e0 + lane];
        float xx = d * scale;
        int i0 = (int)xx;
        i0 = max(0, min(i0, TBL - 2));
        float frac = xx - (float)i0;
        #pragma unroll 4
        for (int j = 0; j < 64; ++j) {
            const int sj = __shfl(src, j);
            const int dj = __shfl(dst, j);
            const int ij = __shfl(i0, j);
            const float fj = __shfl(frac, j);
            const float2 tv = tab2f[(size_t)ij * NF + lane];
            const float filt = fmaf(fj * 256.0f, tv.y, tv.x);
            const float hv = __half2float(h16[(size_t)sj * NF + lane]);
            atomicAdd(agg + (size_t)dj * NF + lane, hv * filt);
        }
    }
    if (gw == 0) {
        for (int e = nbatch << 6; e < n_edges; ++e) {
            const int sj = nbr[e];
            const int dj = nbr[n_edges + e];
            const float d = dist[e];
            float xx = d * scale;
            int ij = (int)xx;
            ij = max(0, min(ij, TBL - 2));
            const float fj = xx - (float)ij;
            const float2 tv = tab2f[(size_t)ij * NF + lane];
            const float filt = fmaf(fj * 256.0f, tv.y, tv.x);
            const float hv = __half2float(h16[(size_t)sj * NF + lane]);
            atomicAdd(agg + (size_t)dj * NF + lane, hv * filt);
        }
    }
}

// ---------------------------------------------------------------------------
// out = ssp(agg @ m_w1.T + m_b1) @ m_w2.T + m_b2  (wave/node, weights in VGPR)
// safe in-place (agg aliases out; row-local)
// ---------------------------------------------------------------------------
__global__ void __launch_bounds__(256) out_mlp_k(const float* __restrict__ agg,
                                                 const float* __restrict__ w1,
                                                 const float* __restrict__ b1,
                                                 const float* __restrict__ w2,
                                                 const float* __restrict__ b2,
                                                 float* __restrict__ out, int n_nodes) {
    const int tid = threadIdx.x;
    const int lane = tid & 63;
    float w1reg[NF], w2reg[NF];
    #pragma unroll
    for (int k = 0; k < NF; k += 4) {
        float4 q1 = *(const float4*)(w1 + (size_t)lane * NF + k);
        w1reg[k] = q1.x; w1reg[k + 1] = q1.y; w1reg[k + 2] = q1.z; w1reg[k + 3] = q1.w;
        float4 q2 = *(const float4*)(w2 + (size_t)lane * NF + k);
        w2reg[k] = q2.x; w2reg[k + 1] = q2.y; w2reg[k + 2] = q2.z; w2reg[k + 3] = q2.w;
    }
    const float bias1 = b1[lane], bias2 = b2[lane];
    const int nwaves = (gridDim.x * blockDim.x) >> 6;
    const int gw = (blockIdx.x * blockDim.x + tid) >> 6;
    for (int n = gw; n < n_nodes; n += nwaves) {
        const float av = agg[(size_t)n * NF + lane];
        float a0 = bias1, a1 = 0.f, a2 = 0.f, a3 = 0.f;
        #pragma unroll
        for (int k = 0; k < NF; k += 4) {
            a0 = fmaf(bcast(av, k),     w1reg[k],     a0);
            a1 = fmaf(bcast(av, k + 1), w1reg[k + 1], a1);
            a2 = fmaf(bcast(av, k + 2), w1reg[k + 2], a2);
            a3 = fmaf(bcast(av, k + 3), w1reg[k + 3], a3);
        }
        const float s = sspf((a0 + a1) + (a2 + a3));
        float o0 = bias2, o1 = 0.f, o2 = 0.f, o3 = 0.f;
        #pragma unroll
        for (int k = 0; k < NF; k += 4) {
            o0 = fmaf(bcast(s, k),     w2reg[k],     o0);
            o1 = fmaf(bcast(s, k + 1), w2reg[k + 1], o1);
            o2 = fmaf(bcast(s, k + 2), w2reg[k + 2], o2);
            o3 = fmaf(bcast(s, k + 3), w2reg[k + 3], o3);
        }
        out[(size_t)n * NF + lane] = (o0 + o1) + (o2 + o3);
    }
}

extern "C" void kernel_launch(void* const* d_in, const int* in_sizes, int n_in,
                              void* d_out, int out_size, void* d_ws, size_t ws_size,
                              hipStream_t stream) {
    const int*   nbr   = (const int*)d_in[0];
    const float* dist  = (const float*)d_in[1];
    const float* x     = (const float*)d_in[2];
    const float* lin_w = (const float*)d_in[3];
    const float* lin_b = (const float*)d_in[4];
    const float* f_w1  = (const float*)d_in[5];
    const float* f_b1  = (const float*)d_in[6];
    const float* f_w2  = (const float*)d_in[7];
    const float* f_b2  = (const float*)d_in[8];
    const float* m_w1  = (const float*)d_in[9];
    const float* m_b1  = (const float*)d_in[10];
    const float* m_w2  = (const float*)d_in[11];
    const float* m_b2  = (const float*)d_in[12];

    const int n_edges = in_sizes[1];
    const int n_nodes = in_sizes[2] / NF;
    const int ngroups = (n_nodes + GRP - 1) / GRP;
    const int chk     = (n_edges + NSC - 1) / NSC;

    float* out = (float*)d_out;
    float* agg = out;   // agg lives in d_out; out_mlp runs in place

    // workspace: h16 | tab2f | cnt | colpre | tot | gbase | payload
    char* ws = (char*)d_ws;
    size_t off = 0;
    auto alloc = [&](size_t bytes) { char* p = ws + off; off = (off + bytes + 255) & ~(size_t)255; return p; };
    __half*   h16     = (__half*)alloc((size_t)n_nodes * NF * sizeof(__half));
    float2*   tab2f   = (float2*)alloc((size_t)TBL * NF * sizeof(float2));
    unsigned* cnt     = (unsigned*)alloc((size_t)NSC * ngroups * sizeof(unsigned));
    unsigned* colpre  = (unsigned*)alloc((size_t)NSC * ngroups * sizeof(unsigned));
    unsigned* tot     = (unsigned*)alloc((size_t)ngroups * sizeof(unsigned));
    unsigned* gbase   = (unsigned*)alloc((size_t)(ngroups + 1) * sizeof(unsigned));
    ull*      payload = (ull*)alloc((size_t)NSC * chk * sizeof(ull));
    const bool sort_path = (off <= ws_size) && (ngroups <= GMAX) && (n_nodes <= (1 << 17));

    build_tab2f_k<<<TBL, 64, 0, stream>>>(f_w1, f_b1, f_w2, f_b2, tab2f);
    prep_k<<<2048, 256, 0, stream>>>(x, lin_w, lin_b, h16, n_nodes);

    if (sort_path) {
        hist_k<<<NSC, 1024, 0, stream>>>(nbr + n_edges, n_edges, ngroups, chk, cnt);
        colscan_k<<<ngroups, 64, 0, stream>>>(cnt, colpre, tot, ngroups);
        base_k<<<1, 64, 0, stream>>>(tot, gbase, ngroups);
        scatter2_k<<<NSC, 1024, 0, stream>>>(nbr, dist, n_edges, ngroups, chk,
                                             colpre, gbase, payload);
        agg_k<<<ngroups, 256, 0, stream>>>(payload, gbase, h16, tab2f, agg, n_nodes);
        oflow2_k<<<ngroups, 64, 0, stream>>>(payload, gbase, h16, tab2f, agg);
    } else {
        hipMemsetAsync(agg, 0, (size_t)n_nodes * NF * sizeof(float), stream);
        edge_k<<<2048, 256, 0, stream>>>(nbr, dist, h16, tab2f, agg, n_edges);
    }
    out_mlp_k<<<1024, 256, 0, stream>>>(agg, m_w1, m_b1, m_w2, m_b2, out, n_nodes);
}

// Round 11
// 256.313 us; speedup vs baseline: 1.0263x; 1.0263x over previous
//
#include <hip/hip_runtime.h>
#include <hip/hip_fp16.h>

#define NF 64
#define KEXP 50
#define TBL 2048
#define CUTF 5.0f
#define LOG2C 0.6931471805599453f
#define GRP 64              // nodes per group (agg block granule)
#define NSC 128             // superchunks (sort blocks)
#define GMAX 2048           // max node-groups (LDS histogram bound)
#define SCAP 1536           // max records per group in agg (mean 1024, +16 sigma)

typedef unsigned long long ull;

__device__ __forceinline__ float sspf(float x) {
    return fmaxf(x, 0.0f) + log1pf(expf(-fabsf(x))) - LOG2C;
}

__device__ __forceinline__ float bcast(float v, int k) {
    return __int_as_float(__builtin_amdgcn_readlane(__float_as_int(v), k));
}

// ---------------------------------------------------------------------------
// half2 lerp table: tabh2[t][f] = ( f_t[f], (f_{t+1}[f]-f_t[f]) / 256 )
// row = NF half2 = 256B
// ---------------------------------------------------------------------------
__global__ void build_tabh2_k(const float* __restrict__ f_w1, const float* __restrict__ f_b1,
                              const float* __restrict__ f_w2, const float* __restrict__ f_b2,
                              __half2* __restrict__ tabh2) {
    __shared__ float rbf_s[KEXP];
    __shared__ float s_s[NF];
    const int t = blockIdx.x;
    const int f = threadIdx.x; // 0..63
    const float delta = CUTF / (float)(KEXP - 1);
    const float coeff = -0.5f / (delta * delta);
    const float dstep = CUTF / (float)(TBL - 1);
    float vals[2];
    for (int p = 0; p < 2; ++p) {
        const int tt = min(t + p, TBL - 1);
        const float d = (float)tt * dstep;
        __syncthreads();
        if (f < KEXP) {
            float dd = d - (float)f * delta;
            rbf_s[f] = expf(coeff * dd * dd);
        }
        __syncthreads();
        float t1 = f_b1[f];
        for (int k = 0; k < KEXP; ++k) t1 = fmaf(rbf_s[k], f_w1[f * KEXP + k], t1);
        __syncthreads();
        s_s[f] = sspf(t1);
        __syncthreads();
        float t2 = f_b2[f];
        for (int k = 0; k < NF; ++k) t2 = fmaf(s_s[k], f_w2[f * NF + k], t2);
        vals[p] = t2;
    }
    tabh2[(size_t)t * NF + f] =
        __floats2half2_rn(vals[0], (vals[1] - vals[0]) * (1.0f / 256.0f));
}

// ---------------------------------------------------------------------------
// prep: h16 = fp16(x @ lin_w.T + lin_b)  (wave/node, weights in VGPR)
// ---------------------------------------------------------------------------
__global__ void __launch_bounds__(256) prep_k(
    const float* __restrict__ x, const float* __restrict__ w, const float* __restrict__ b,
    __half* __restrict__ h16, int n_nodes)
{
    const int tid = threadIdx.x;
    const int lane = tid & 63;
    float wreg[NF];
    #pragma unroll
    for (int k = 0; k < NF; k += 4) {
        float4 q = *(const float4*)(w + (size_t)lane * NF + k);
        wreg[k] = q.x; wreg[k + 1] = q.y; wreg[k + 2] = q.z; wreg[k + 3] = q.w;
    }
    const float bias = b[lane];
    const int nwaves = (gridDim.x * blockDim.x) >> 6;
    const int gw = (blockIdx.x * blockDim.x + tid) >> 6;
    for (int n = gw; n < n_nodes; n += nwaves) {
        const float xv = x[(size_t)n * NF + lane];
        float a0 = bias, a1 = 0.f, a2 = 0.f, a3 = 0.f;
        #pragma unroll
        for (int k = 0; k < NF; k += 4) {
            a0 = fmaf(bcast(xv, k),     wreg[k],     a0);
            a1 = fmaf(bcast(xv, k + 1), wreg[k + 1], a1);
            a2 = fmaf(bcast(xv, k + 2), wreg[k + 2], a2);
            a3 = fmaf(bcast(xv, k + 3), wreg[k + 3], a3);
        }
        h16[(size_t)n * NF + lane] = __float2half((a0 + a1) + (a2 + a3));
    }
}

// ---------------------------------------------------------------------------
// hist: per superchunk, RAW histogram of dst-groups -> cnt[c][g] (coalesced)
// ---------------------------------------------------------------------------
__global__ void __launch_bounds__(1024) hist_k(const int* __restrict__ nbr_dst,
                                               int n_edges, int ngroups, int chk,
                                               unsigned* __restrict__ cnt) {
    __shared__ unsigned cnt_s[GMAX];
    const int tid = threadIdx.x;
    const int c = blockIdx.x;
    const int e0 = c * chk;
    const int e1 = min(e0 + chk, n_edges);
    const int m = max(e1 - e0, 0);
    for (int g = tid; g < ngroups; g += 1024) cnt_s[g] = 0u;
    __syncthreads();
    for (int i = tid; i < m; i += 1024)
        atomicAdd(&cnt_s[(unsigned)nbr_dst[e0 + i] >> 6], 1u);
    __syncthreads();
    const size_t ob = (size_t)c * ngroups;
    for (int g = tid; g < ngroups; g += 1024) cnt[ob + g] = cnt_s[g];
}

// ---------------------------------------------------------------------------
// colscan: per group g, exclusive scan of cnt[c][g] along c -> colpre[c][g],
// and per-group total -> tot[g]. One wave, 2 chunks per lane.
// ---------------------------------------------------------------------------
__global__ void __launch_bounds__(64) colscan_k(const unsigned* __restrict__ cnt,
                                                unsigned* __restrict__ colpre,
                                                unsigned* __restrict__ tot, int ngroups) {
    const int g = blockIdx.x;
    const int lane = threadIdx.x;
    const unsigned a = cnt[(size_t)(2 * lane) * ngroups + g];
    const unsigned b = cnt[(size_t)(2 * lane + 1) * ngroups + g];
    const unsigned s = a + b;
    unsigned run = s;
    #pragma unroll
    for (int d = 1; d < 64; d <<= 1) {
        const unsigned t = __shfl_up(run, d, 64);
        if (lane >= d) run += t;
    }
    const unsigned pre = run - s;
    colpre[(size_t)(2 * lane) * ngroups + g] = pre;
    colpre[(size_t)(2 * lane + 1) * ngroups + g] = pre + a;
    if (lane == 63) tot[g] = run;
}

// ---------------------------------------------------------------------------
// base: exclusive scan over group totals -> gbase[0..ngroups]
// ---------------------------------------------------------------------------
__global__ void __launch_bounds__(64) base_k(const unsigned* __restrict__ tot,
                                             unsigned* __restrict__ gbase, int ngroups) {
    const int lane = threadIdx.x;
    unsigned carry = 0u;
    for (int base = 0; base < ngroups; base += 64) {
        const int g = base + lane;
        const unsigned v = (g < ngroups) ? tot[g] : 0u;
        unsigned run = v;
        #pragma unroll
        for (int d = 1; d < 64; d <<= 1) {
            const unsigned t = __shfl_up(run, d, 64);
            if (lane >= d) run += t;
        }
        if (g < ngroups) gbase[g] = carry + run - v;
        carry += (unsigned)__shfl((int)run, 63, 64);
    }
    if (lane == 0) gbase[ngroups] = carry;
}

// ---------------------------------------------------------------------------
// scatter2: write records to FINAL globally-sorted-by-group positions.
// rec: lo = (i0<<8)|fr8  (tab byte off = lo & ~255, half2 row = 256B)
//      hi = (src<<7)|dstrow (h byte off = hi & ~127)
// ---------------------------------------------------------------------------
__global__ void __launch_bounds__(1024) scatter2_k(const int* __restrict__ nbr,
                                                   const float* __restrict__ dist,
                                                   int n_edges, int ngroups, int chk,
                                                   const unsigned* __restrict__ colpre,
                                                   const unsigned* __restrict__ gbase,
                                                   ull* __restrict__ payload) {
    __shared__ unsigned cur_s[GMAX];
    const int tid = threadIdx.x;
    const int c = blockIdx.x;
    const int e0 = c * chk;
    const int e1 = min(e0 + chk, n_edges);
    const int m = max(e1 - e0, 0);
    const size_t ob = (size_t)c * ngroups;
    for (int g = tid; g < ngroups; g += 1024) cur_s[g] = gbase[g] + colpre[ob + g];
    __syncthreads();
    const float scale = (float)(TBL - 1) / CUTF;
    for (int i = tid; i < m; i += 1024) {
        const int e = e0 + i;
        const unsigned dst = (unsigned)nbr[n_edges + e];
        const unsigned src = (unsigned)nbr[e];
        const float xx = dist[e] * scale;
        int i0 = (int)xx;
        i0 = max(0, min(i0, TBL - 2));
        const float fr = xx - (float)i0;
        const unsigned fr8 = min((unsigned)(fr * 256.0f), 255u);
        const ull rec = (ull)(((unsigned)i0 << 8) | fr8) |
                        ((ull)((src << 7) | (dst & 63u)) << 32);
        const unsigned pos = atomicAdd(&cur_s[dst >> 6], 1u);
        payload[pos] = rec;
    }
}

// ---------------------------------------------------------------------------
// agg: block = 64-node group. Single global payload read into raw LDS (+count),
// LDS->LDS row place, then gather-accumulate with unroll-8 (no atomics).
// ---------------------------------------------------------------------------
__global__ void __launch_bounds__(256) agg_k(
    const ull* __restrict__ payload, const unsigned* __restrict__ gbase,
    const __half* __restrict__ h16, const __half2* __restrict__ tabh2,
    float* __restrict__ agg, int n_nodes)
{
    __shared__ ull raw_s[SCAP];
    __shared__ ull sorted_s[SCAP];
    __shared__ unsigned cnt_s[GRP];
    __shared__ unsigned base_s[GRP];
    __shared__ unsigned cur_s[GRP];
    const int tid = threadIdx.x;
    const int lane = tid & 63;
    const int wid = tid >> 6;   // 0..3
    const int g = blockIdx.x;
    const unsigned beg = gbase[g];
    const unsigned end = gbase[g + 1];
    const unsigned tot = min(end - beg, (unsigned)SCAP);

    if (tid < GRP) cnt_s[tid] = 0u;
    __syncthreads();
    // Phase A: single coalesced global read -> raw LDS, count rows
    for (unsigned i = tid; i < tot; i += 256u) {
        const ull r = payload[beg + i];
        raw_s[i] = r;
        atomicAdd(&cnt_s[(unsigned)(r >> 32) & 63u], 1u);
    }
    __syncthreads();
    // exclusive scan over 64 row counts
    if (tid < GRP) {
        const unsigned c = cnt_s[tid];
        unsigned run = c;
        #pragma unroll
        for (int d = 1; d < 64; d <<= 1) {
            const unsigned t = __shfl_up(run, d, 64);
            if (tid >= d) run += t;
        }
        base_s[tid] = run - c;
        cur_s[tid]  = run - c;
    }
    __syncthreads();
    // Phase B: place by row (LDS -> LDS)
    for (unsigned i = tid; i < tot; i += 256u) {
        const ull r = raw_s[i];
        const unsigned pos = atomicAdd(&cur_s[(unsigned)(r >> 32) & 63u], 1u);
        sorted_s[pos] = r;
    }
    __syncthreads();
    // Phase C: gather-accumulate; one coalesced store per row
    const char* tabB = (const char*)tabh2 + (lane << 2);
    const char* hB   = (const char*)h16 + (lane << 1);
    auto ev = [&](ull rec) -> float {
        const unsigned lo = (unsigned)rec;
        const unsigned hi = (unsigned)(rec >> 32);
        const float2 t = __half22float2(*(const __half2*)(tabB + (lo & 0xFFFFFF00u)));
        const float hv = __half2float(*(const __half*)(hB + (hi & 0xFFFFFF80u)));
        return hv * fmaf((float)(lo & 255u), t.y, t.x);
    };
    const int n0 = g * GRP;
    for (int rr = 0; rr < 16; ++rr) {
        const int r = (wid << 4) + rr;
        unsigned i = base_s[r];
        const unsigned e = cur_s[r];
        float acc0 = 0.f, acc1 = 0.f;
        for (; i + 8u <= e; i += 8u) {
            const ull r0 = sorted_s[i];
            const ull r1 = sorted_s[i + 1];
            const ull r2 = sorted_s[i + 2];
            const ull r3 = sorted_s[i + 3];
            const ull r4 = sorted_s[i + 4];
            const ull r5 = sorted_s[i + 5];
            const ull r6 = sorted_s[i + 6];
            const ull r7 = sorted_s[i + 7];
            acc0 += (ev(r0) + ev(r1)) + (ev(r2) + ev(r3));
            acc1 += (ev(r4) + ev(r5)) + (ev(r6) + ev(r7));
        }
        for (; i < e; ++i) acc0 += ev(sorted_s[i]);
        const int n = n0 + r;
        if (n < n_nodes) agg[(size_t)n * NF + lane] = acc0 + acc1;
    }
}

// ---------------------------------------------------------------------------
// overflow fixup: groups with >SCAP records process the tail directly from
// the sorted payload with global atomics (normally zero work)
// ---------------------------------------------------------------------------
__global__ void __launch_bounds__(64) oflow2_k(const ull* __restrict__ payload,
                                               const unsigned* __restrict__ gbase,
                                               const __half* __restrict__ h16,
                                               const __half2* __restrict__ tabh2,
                                               float* __restrict__ agg) {
    const int g = blockIdx.x;
    const unsigned beg = gbase[g];
    const unsigned end = gbase[g + 1];
    if (end - beg <= (unsigned)SCAP) return;
    const int lane = threadIdx.x;
    const char* tabB = (const char*)tabh2 + (lane << 2);
    const char* hB   = (const char*)h16 + (lane << 1);
    for (unsigned i = beg + SCAP; i < end; ++i) {
        const ull rec = payload[i];
        const unsigned lo = (unsigned)rec;
        const unsigned hi = (unsigned)(rec >> 32);
        const float2 t = __half22float2(*(const __half2*)(tabB + (lo & 0xFFFFFF00u)));
        const float hv = __half2float(*(const __half*)(hB + (hi & 0xFFFFFF80u)));
        const float filt = fmaf((float)(lo & 255u), t.y, t.x);
        const unsigned row = (unsigned)g * GRP + (hi & 63u);
        atomicAdd(agg + (size_t)row * NF + lane, hv * filt);
    }
}

// ---------------------------------------------------------------------------
// fallback edge kernel (direct atomic scatter-add) — used only if ws too small
// ---------------------------------------------------------------------------
__global__ void edge_k(const int* __restrict__ nbr, const float* __restrict__ dist,
                       const __half* __restrict__ h16, const __half2* __restrict__ tabh2,
                       float* __restrict__ agg, int n_edges) {
    const int tid = threadIdx.x;
    const int lane = tid & 63;
    const int nwaves = (gridDim.x * blockDim.x) >> 6;
    const int gw = (blockIdx.x * blockDim.x + tid) >> 6;
    const float scale = (float)(TBL - 1) / CUTF;
    const int nbatch = n_edges >> 6;
    for (int bb = gw; bb < nbatch; bb += nwaves) {
        const int e0 = bb << 6;
        int src = nbr[e0 + lane];
        int dst = nbr[n_edges + e0 + lane];
        float d = dist[e0 + lane];
        float xx = d * scale;
        int i0 = (int)xx;
        i0 = max(0, min(i0, TBL - 2));
        float frac = xx - (float)i0;
        #pragma unroll 4
        for (int j = 0; j < 64; ++j) {
            const int sj = __shfl(src, j);
            const int dj = __shfl(dst, j);
            const int ij = __shfl(i0, j);
            const float fj = __shfl(frac, j);
            const float2 tv = __half22float2(tabh2[(size_t)ij * NF + lane]);
            const float filt = fmaf(fj * 256.0f, tv.y, tv.x);
            const float hv = __half2float(h16[(size_t)sj * NF + lane]);
            atomicAdd(agg + (size_t)dj * NF + lane, hv * filt);
        }
    }
    if (gw == 0) {
        for (int e = nbatch << 6; e < n_edges; ++e) {
            const int sj = nbr[e];
            const int dj = nbr[n_edges + e];
            const float d = dist[e];
            float xx = d * scale;
            int ij = (int)xx;
            ij = max(0, min(ij, TBL - 2));
            const float fj = xx - (float)ij;
            const float2 tv = __half22float2(tabh2[(size_t)ij * NF + lane]);
            const float filt = fmaf(fj * 256.0f, tv.y, tv.x);
            const float hv = __half2float(h16[(size_t)sj * NF + lane]);
            atomicAdd(agg + (size_t)dj * NF + lane, hv * filt);
        }
    }
}

// ---------------------------------------------------------------------------
// out = ssp(agg @ m_w1.T + m_b1) @ m_w2.T + m_b2  (wave/node, weights in VGPR)
// safe in-place (agg aliases out; row-local)
// ---------------------------------------------------------------------------
__global__ void __launch_bounds__(256) out_mlp_k(const float* __restrict__ agg,
                                                 const float* __restrict__ w1,
                                                 const float* __restrict__ b1,
                                                 const float* __restrict__ w2,
                                                 const float* __restrict__ b2,
                                                 float* __restrict__ out, int n_nodes) {
    const int tid = threadIdx.x;
    const int lane = tid & 63;
    float w1reg[NF], w2reg[NF];
    #pragma unroll
    for (int k = 0; k < NF; k += 4) {
        float4 q1 = *(const float4*)(w1 + (size_t)lane * NF + k);
        w1reg[k] = q1.x; w1reg[k + 1] = q1.y; w1reg[k + 2] = q1.z; w1reg[k + 3] = q1.w;
        float4 q2 = *(const float4*)(w2 + (size_t)lane * NF + k);
        w2reg[k] = q2.x; w2reg[k + 1] = q2.y; w2reg[k + 2] = q2.z; w2reg[k + 3] = q2.w;
    }
    const float bias1 = b1[lane], bias2 = b2[lane];
    const int nwaves = (gridDim.x * blockDim.x) >> 6;
    const int gw = (blockIdx.x * blockDim.x + tid) >> 6;
    for (int n = gw; n < n_nodes; n += nwaves) {
        const float av = agg[(size_t)n * NF + lane];
        float a0 = bias1, a1 = 0.f, a2 = 0.f, a3 = 0.f;
        #pragma unroll
        for (int k = 0; k < NF; k += 4) {
            a0 = fmaf(bcast(av, k),     w1reg[k],     a0);
            a1 = fmaf(bcast(av, k + 1), w1reg[k + 1], a1);
            a2 = fmaf(bcast(av, k + 2), w1reg[k + 2], a2);
            a3 = fmaf(bcast(av, k + 3), w1reg[k + 3], a3);
        }
        const float s = sspf((a0 + a1) + (a2 + a3));
        float o0 = bias2, o1 = 0.f, o2 = 0.f, o3 = 0.f;
        #pragma unroll
        for (int k = 0; k < NF; k += 4) {
            o0 = fmaf(bcast(s, k),     w2reg[k],     o0);
            o1 = fmaf(bcast(s, k + 1), w2reg[k + 1], o1);
            o2 = fmaf(bcast(s, k + 2), w2reg[k + 2], o2);
            o3 = fmaf(bcast(s, k + 3), w2reg[k + 3], o3);
        }
        out[(size_t)n * NF + lane] = (o0 + o1) + (o2 + o3);
    }
}

extern "C" void kernel_launch(void* const* d_in, const int* in_sizes, int n_in,
                              void* d_out, int out_size, void* d_ws, size_t ws_size,
                              hipStream_t stream) {
    const int*   nbr   = (const int*)d_in[0];
    const float* dist  = (const float*)d_in[1];
    const float* x     = (const float*)d_in[2];
    const float* lin_w = (const float*)d_in[3];
    const float* lin_b = (const float*)d_in[4];
    const float* f_w1  = (const float*)d_in[5];
    const float* f_b1  = (const float*)d_in[6];
    const float* f_w2  = (const float*)d_in[7];
    const float* f_b2  = (const float*)d_in[8];
    const float* m_w1  = (const float*)d_in[9];
    const float* m_b1  = (const float*)d_in[10];
    const float* m_w2  = (const float*)d_in[11];
    const float* m_b2  = (const float*)d_in[12];

    const int n_edges = in_sizes[1];
    const int n_nodes = in_sizes[2] / NF;
    const int ngroups = (n_nodes + GRP - 1) / GRP;
    const int chk     = (n_edges + NSC - 1) / NSC;

    float* out = (float*)d_out;
    float* agg = out;   // agg lives in d_out; out_mlp runs in place

    // workspace: h16 | tabh2 | cnt | colpre | tot | gbase | payload
    char* ws = (char*)d_ws;
    size_t off = 0;
    auto alloc = [&](size_t bytes) { char* p = ws + off; off = (off + bytes + 255) & ~(size_t)255; return p; };
    __half*   h16     = (__half*)alloc((size_t)n_nodes * NF * sizeof(__half));
    __half2*  tabh2   = (__half2*)alloc((size_t)TBL * NF * sizeof(__half2));
    unsigned* cnt     = (unsigned*)alloc((size_t)NSC * ngroups * sizeof(unsigned));
    unsigned* colpre  = (unsigned*)alloc((size_t)NSC * ngroups * sizeof(unsigned));
    unsigned* tot     = (unsigned*)alloc((size_t)ngroups * sizeof(unsigned));
    unsigned* gbase   = (unsigned*)alloc((size_t)(ngroups + 1) * sizeof(unsigned));
    ull*      payload = (ull*)alloc((size_t)NSC * chk * sizeof(ull));
    const bool sort_path = (off <= ws_size) && (ngroups <= GMAX) && (n_nodes <= (1 << 17));

    build_tabh2_k<<<TBL, 64, 0, stream>>>(f_w1, f_b1, f_w2, f_b2, tabh2);
    prep_k<<<2048, 256, 0, stream>>>(x, lin_w, lin_b, h16, n_nodes);

    if (sort_path) {
        hist_k<<<NSC, 1024, 0, stream>>>(nbr + n_edges, n_edges, ngroups, chk, cnt);
        colscan_k<<<ngroups, 64, 0, stream>>>(cnt, colpre, tot, ngroups);
        base_k<<<1, 64, 0, stream>>>(tot, gbase, ngroups);
        scatter2_k<<<NSC, 1024, 0, stream>>>(nbr, dist, n_edges, ngroups, chk,
                                             colpre, gbase, payload);
        agg_k<<<ngroups, 256, 0, stream>>>(payload, gbase, h16, tabh2, agg, n_nodes);
        oflow2_k<<<ngroups, 64, 0, stream>>>(payload, gbase, h16, tabh2, agg);
    } else {
        hipMemsetAsync(agg, 0, (size_t)n_nodes * NF * sizeof(float), stream);
        edge_k<<<2048, 256, 0, stream>>>(nbr, dist, h16, tabh2, agg, n_edges);
    }
    out_mlp_k<<<2048, 256, 0, stream>>>(agg, m_w1, m_b1, m_w2, m_b2, out, n_nodes);
}

// Round 12
// 205.381 us; speedup vs baseline: 1.2808x; 1.2480x over previous
//
#include <hip/hip_runtime.h>
#include <hip/hip_fp16.h>

#define NF 64
#define KEXP 50
#define TBL 2048
#define CUTF 5.0f
#define LOG2C 0.6931471805599453f
#define GRP 64              // nodes per group (agg block granule)
#define NSC 128             // superchunks (sort blocks)
#define GMAX 2048           // max node-groups (LDS histogram bound)
#define SCAP 1536           // max records per group in agg (mean 1024, +16 sigma)

typedef unsigned long long ull;
typedef _Float16 f16x8 __attribute__((ext_vector_type(8)));
typedef float f32x4 __attribute__((ext_vector_type(4)));

__device__ __forceinline__ float sspf(float x) {
    return fmaxf(x, 0.0f) + log1pf(expf(-fabsf(x))) - LOG2C;
}

__device__ __forceinline__ float bcast(float v, int k) {
    return __int_as_float(__builtin_amdgcn_readlane(__float_as_int(v), k));
}

// load 8 consecutive fp32 from row-major w[f][k0..k0+7] as f16x8 (MFMA B-frag)
__device__ __forceinline__ f16x8 load_wfrag(const float* __restrict__ w, int f, int k0) {
    const float4 q0 = *(const float4*)(w + (size_t)f * NF + k0);
    const float4 q1 = *(const float4*)(w + (size_t)f * NF + k0 + 4);
    f16x8 r;
    r[0] = (_Float16)q0.x; r[1] = (_Float16)q0.y; r[2] = (_Float16)q0.z; r[3] = (_Float16)q0.w;
    r[4] = (_Float16)q1.x; r[5] = (_Float16)q1.y; r[6] = (_Float16)q1.z; r[7] = (_Float16)q1.w;
    return r;
}

__device__ __forceinline__ f16x8 load_afrag_f32(const float* __restrict__ p) {
    const float4 q0 = *(const float4*)(p);
    const float4 q1 = *(const float4*)(p + 4);
    f16x8 r;
    r[0] = (_Float16)q0.x; r[1] = (_Float16)q0.y; r[2] = (_Float16)q0.z; r[3] = (_Float16)q0.w;
    r[4] = (_Float16)q1.x; r[5] = (_Float16)q1.y; r[6] = (_Float16)q1.z; r[7] = (_Float16)q1.w;
    return r;
}

// ---------------------------------------------------------------------------
// half2 lerp table: tabh2[t][f] = ( f_t[f], (f_{t+1}[f]-f_t[f]) / 256 )
// ---------------------------------------------------------------------------
__global__ void build_tabh2_k(const float* __restrict__ f_w1, const float* __restrict__ f_b1,
                              const float* __restrict__ f_w2, const float* __restrict__ f_b2,
                              __half2* __restrict__ tabh2) {
    __shared__ float rbf_s[KEXP];
    __shared__ float s_s[NF];
    const int t = blockIdx.x;
    const int f = threadIdx.x; // 0..63
    const float delta = CUTF / (float)(KEXP - 1);
    const float coeff = -0.5f / (delta * delta);
    const float dstep = CUTF / (float)(TBL - 1);
    float vals[2];
    for (int p = 0; p < 2; ++p) {
        const int tt = min(t + p, TBL - 1);
        const float d = (float)tt * dstep;
        __syncthreads();
        if (f < KEXP) {
            float dd = d - (float)f * delta;
            rbf_s[f] = expf(coeff * dd * dd);
        }
        __syncthreads();
        float t1 = f_b1[f];
        for (int k = 0; k < KEXP; ++k) t1 = fmaf(rbf_s[k], f_w1[f * KEXP + k], t1);
        __syncthreads();
        s_s[f] = sspf(t1);
        __syncthreads();
        float t2 = f_b2[f];
        for (int k = 0; k < NF; ++k) t2 = fmaf(s_s[k], f_w2[f * NF + k], t2);
        vals[p] = t2;
    }
    tabh2[(size_t)t * NF + f] =
        __floats2half2_rn(vals[0], (vals[1] - vals[0]) * (1.0f / 256.0f));
}

// ---------------------------------------------------------------------------
// prep (MFMA): h16 = fp16(x @ lin_w.T + lin_b). Wave per 16-node tile.
// ---------------------------------------------------------------------------
__global__ void __launch_bounds__(256) prep_k(
    const float* __restrict__ x, const float* __restrict__ w, const float* __restrict__ b,
    __half* __restrict__ h16, int n_nodes)
{
    __shared__ _Float16 stile[4][16][72];
    const int tid = threadIdx.x;
    const int lane = tid & 63;
    const int wid = tid >> 6;
    const int col = lane & 15;
    const int quad = lane >> 4;

    f16x8 bw[4][2];
    float bv[4];
    #pragma unroll
    for (int t = 0; t < 4; ++t) {
        #pragma unroll
        for (int kb = 0; kb < 2; ++kb)
            bw[t][kb] = load_wfrag(w, 16 * t + col, kb * 32 + quad * 8);
        bv[t] = b[16 * t + col];
    }

    const int ntiles = (n_nodes + 15) >> 4;
    for (int tile = blockIdx.x * 4 + wid; tile < ntiles; tile += gridDim.x * 4) {
        const int n0 = tile << 4;
        const int nr = min(n0 + col, n_nodes - 1);
        f16x8 a[2];
        #pragma unroll
        for (int kb = 0; kb < 2; ++kb)
            a[kb] = load_afrag_f32(x + (size_t)nr * NF + kb * 32 + quad * 8);
        f32x4 acc[4];
        #pragma unroll
        for (int t = 0; t < 4; ++t) acc[t] = (f32x4){bv[t], bv[t], bv[t], bv[t]};
        #pragma unroll
        for (int t = 0; t < 4; ++t)
            #pragma unroll
            for (int kb = 0; kb < 2; ++kb)
                acc[t] = __builtin_amdgcn_mfma_f32_16x16x32_f16(a[kb], bw[t][kb], acc[t], 0, 0, 0);
        #pragma unroll
        for (int t = 0; t < 4; ++t)
            #pragma unroll
            for (int r = 0; r < 4; ++r)
                stile[wid][quad * 4 + r][16 * t + col] = (_Float16)acc[t][r];
        __threadfence_block();
        // coalesced fp16 write-out: 16 rows x 128B
        #pragma unroll
        for (int it = 0; it < 2; ++it) {
            const int chunk = it * 64 + lane;
            const int row = chunk >> 3;
            const int off = (chunk & 7) * 8;
            const int n = n0 + row;
            if (n < n_nodes)
                *(uint4*)(h16 + (size_t)n * NF + off) = *(const uint4*)&stile[wid][row][off];
        }
        __threadfence_block();
    }
}

// ---------------------------------------------------------------------------
// hist: per superchunk, RAW histogram of dst-groups -> cnt[c][g] (coalesced)
// ---------------------------------------------------------------------------
__global__ void __launch_bounds__(1024) hist_k(const int* __restrict__ nbr_dst,
                                               int n_edges, int ngroups, int chk,
                                               unsigned* __restrict__ cnt) {
    __shared__ unsigned cnt_s[GMAX];
    const int tid = threadIdx.x;
    const int c = blockIdx.x;
    const int e0 = c * chk;
    const int e1 = min(e0 + chk, n_edges);
    const int m = max(e1 - e0, 0);
    for (int g = tid; g < ngroups; g += 1024) cnt_s[g] = 0u;
    __syncthreads();
    for (int i = tid; i < m; i += 1024)
        atomicAdd(&cnt_s[(unsigned)nbr_dst[e0 + i] >> 6], 1u);
    __syncthreads();
    const size_t ob = (size_t)c * ngroups;
    for (int g = tid; g < ngroups; g += 1024) cnt[ob + g] = cnt_s[g];
}

// ---------------------------------------------------------------------------
// colscan: per group g, exclusive scan of cnt[c][g] along c -> colpre[c][g]
// ---------------------------------------------------------------------------
__global__ void __launch_bounds__(64) colscan_k(const unsigned* __restrict__ cnt,
                                                unsigned* __restrict__ colpre,
                                                unsigned* __restrict__ tot, int ngroups) {
    const int g = blockIdx.x;
    const int lane = threadIdx.x;
    const unsigned a = cnt[(size_t)(2 * lane) * ngroups + g];
    const unsigned b = cnt[(size_t)(2 * lane + 1) * ngroups + g];
    const unsigned s = a + b;
    unsigned run = s;
    #pragma unroll
    for (int d = 1; d < 64; d <<= 1) {
        const unsigned t = __shfl_up(run, d, 64);
        if (lane >= d) run += t;
    }
    const unsigned pre = run - s;
    colpre[(size_t)(2 * lane) * ngroups + g] = pre;
    colpre[(size_t)(2 * lane + 1) * ngroups + g] = pre + a;
    if (lane == 63) tot[g] = run;
}

// ---------------------------------------------------------------------------
// base: exclusive scan over group totals -> gbase[0..ngroups]
// ---------------------------------------------------------------------------
__global__ void __launch_bounds__(64) base_k(const unsigned* __restrict__ tot,
                                             unsigned* __restrict__ gbase, int ngroups) {
    const int lane = threadIdx.x;
    unsigned carry = 0u;
    for (int base = 0; base < ngroups; base += 64) {
        const int g = base + lane;
        const unsigned v = (g < ngroups) ? tot[g] : 0u;
        unsigned run = v;
        #pragma unroll
        for (int d = 1; d < 64; d <<= 1) {
            const unsigned t = __shfl_up(run, d, 64);
            if (lane >= d) run += t;
        }
        if (g < ngroups) gbase[g] = carry + run - v;
        carry += (unsigned)__shfl((int)run, 63, 64);
    }
    if (lane == 0) gbase[ngroups] = carry;
}

// ---------------------------------------------------------------------------
// scatter2: write records to FINAL globally-sorted-by-group positions.
// rec: lo = (i0<<8)|fr8 ; hi = (src<<7)|dstrow
// ---------------------------------------------------------------------------
__global__ void __launch_bounds__(1024) scatter2_k(const int* __restrict__ nbr,
                                                   const float* __restrict__ dist,
                                                   int n_edges, int ngroups, int chk,
                                                   const unsigned* __restrict__ colpre,
                                                   const unsigned* __restrict__ gbase,
                                                   ull* __restrict__ payload) {
    __shared__ unsigned cur_s[GMAX];
    const int tid = threadIdx.x;
    const int c = blockIdx.x;
    const int e0 = c * chk;
    const int e1 = min(e0 + chk, n_edges);
    const int m = max(e1 - e0, 0);
    const size_t ob = (size_t)c * ngroups;
    for (int g = tid; g < ngroups; g += 1024) cur_s[g] = gbase[g] + colpre[ob + g];
    __syncthreads();
    const float scale = (float)(TBL - 1) / CUTF;
    for (int i = tid; i < m; i += 1024) {
        const int e = e0 + i;
        const unsigned dst = (unsigned)nbr[n_edges + e];
        const unsigned src = (unsigned)nbr[e];
        const float xx = dist[e] * scale;
        int i0 = (int)xx;
        i0 = max(0, min(i0, TBL - 2));
        const float fr = xx - (float)i0;
        const unsigned fr8 = min((unsigned)(fr * 256.0f), 255u);
        const ull rec = (ull)(((unsigned)i0 << 8) | fr8) |
                        ((ull)((src << 7) | (dst & 63u)) << 32);
        const unsigned pos = atomicAdd(&cur_s[dst >> 6], 1u);
        payload[pos] = rec;
    }
}

// ---------------------------------------------------------------------------
// agg: block = 64-node group. Single global payload read into raw LDS (+count),
// LDS->LDS row place, then gather-accumulate with unroll-8 (no atomics).
// ---------------------------------------------------------------------------
__global__ void __launch_bounds__(256) agg_k(
    const ull* __restrict__ payload, const unsigned* __restrict__ gbase,
    const __half* __restrict__ h16, const __half2* __restrict__ tabh2,
    float* __restrict__ agg, int n_nodes)
{
    __shared__ ull raw_s[SCAP];
    __shared__ ull sorted_s[SCAP];
    __shared__ unsigned cnt_s[GRP];
    __shared__ unsigned base_s[GRP];
    __shared__ unsigned cur_s[GRP];
    const int tid = threadIdx.x;
    const int lane = tid & 63;
    const int wid = tid >> 6;   // 0..3
    const int g = blockIdx.x;
    const unsigned beg = gbase[g];
    const unsigned end = gbase[g + 1];
    const unsigned tot = min(end - beg, (unsigned)SCAP);

    if (tid < GRP) cnt_s[tid] = 0u;
    __syncthreads();
    for (unsigned i = tid; i < tot; i += 256u) {
        const ull r = payload[beg + i];
        raw_s[i] = r;
        atomicAdd(&cnt_s[(unsigned)(r >> 32) & 63u], 1u);
    }
    __syncthreads();
    if (tid < GRP) {
        const unsigned c = cnt_s[tid];
        unsigned run = c;
        #pragma unroll
        for (int d = 1; d < 64; d <<= 1) {
            const unsigned t = __shfl_up(run, d, 64);
            if (tid >= d) run += t;
        }
        base_s[tid] = run - c;
        cur_s[tid]  = run - c;
    }
    __syncthreads();
    for (unsigned i = tid; i < tot; i += 256u) {
        const ull r = raw_s[i];
        const unsigned pos = atomicAdd(&cur_s[(unsigned)(r >> 32) & 63u], 1u);
        sorted_s[pos] = r;
    }
    __syncthreads();
    const char* tabB = (const char*)tabh2 + (lane << 2);
    const char* hB   = (const char*)h16 + (lane << 1);
    auto ev = [&](ull rec) -> float {
        const unsigned lo = (unsigned)rec;
        const unsigned hi = (unsigned)(rec >> 32);
        const float2 t = __half22float2(*(const __half2*)(tabB + (lo & 0xFFFFFF00u)));
        const float hv = __half2float(*(const __half*)(hB + (hi & 0xFFFFFF80u)));
        return hv * fmaf((float)(lo & 255u), t.y, t.x);
    };
    const int n0 = g * GRP;
    for (int rr = 0; rr < 16; ++rr) {
        const int r = (wid << 4) + rr;
        unsigned i = base_s[r];
        const unsigned e = cur_s[r];
        float acc0 = 0.f, acc1 = 0.f;
        for (; i + 8u <= e; i += 8u) {
            const ull r0 = sorted_s[i];
            const ull r1 = sorted_s[i + 1];
            const ull r2 = sorted_s[i + 2];
            const ull r3 = sorted_s[i + 3];
            const ull r4 = sorted_s[i + 4];
            const ull r5 = sorted_s[i + 5];
            const ull r6 = sorted_s[i + 6];
            const ull r7 = sorted_s[i + 7];
            acc0 += (ev(r0) + ev(r1)) + (ev(r2) + ev(r3));
            acc1 += (ev(r4) + ev(r5)) + (ev(r6) + ev(r7));
        }
        for (; i < e; ++i) acc0 += ev(sorted_s[i]);
        const int n = n0 + r;
        if (n < n_nodes) agg[(size_t)n * NF + lane] = acc0 + acc1;
    }
}

// ---------------------------------------------------------------------------
// overflow fixup: groups with >SCAP records (normally zero work)
// ---------------------------------------------------------------------------
__global__ void __launch_bounds__(64) oflow2_k(const ull* __restrict__ payload,
                                               const unsigned* __restrict__ gbase,
                                               const __half* __restrict__ h16,
                                               const __half2* __restrict__ tabh2,
                                               float* __restrict__ agg) {
    const int g = blockIdx.x;
    const unsigned beg = gbase[g];
    const unsigned end = gbase[g + 1];
    if (end - beg <= (unsigned)SCAP) return;
    const int lane = threadIdx.x;
    const char* tabB = (const char*)tabh2 + (lane << 2);
    const char* hB   = (const char*)h16 + (lane << 1);
    for (unsigned i = beg + SCAP; i < end; ++i) {
        const ull rec = payload[i];
        const unsigned lo = (unsigned)rec;
        const unsigned hi = (unsigned)(rec >> 32);
        const float2 t = __half22float2(*(const __half2*)(tabB + (lo & 0xFFFFFF00u)));
        const float hv = __half2float(*(const __half*)(hB + (hi & 0xFFFFFF80u)));
        const float filt = fmaf((float)(lo & 255u), t.y, t.x);
        const unsigned row = (unsigned)g * GRP + (hi & 63u);
        atomicAdd(agg + (size_t)row * NF + lane, hv * filt);
    }
}

// ---------------------------------------------------------------------------
// fallback edge kernel (direct atomic scatter-add) — used only if ws too small
// ---------------------------------------------------------------------------
__global__ void edge_k(const int* __restrict__ nbr, const float* __restrict__ dist,
                       const __half* __restrict__ h16, const __half2* __restrict__ tabh2,
                       float* __restrict__ agg, int n_edges) {
    const int tid = threadIdx.x;
    const int lane = tid & 63;
    const int nwaves = (gridDim.x * blockDim.x) >> 6;
    const int gw = (blockIdx.x * blockDim.x + tid) >> 6;
    const float scale = (float)(TBL - 1) / CUTF;
    const int nbatch = n_edges >> 6;
    for (int bb = gw; bb < nbatch; bb += nwaves) {
        const int e0 = bb << 6;
        int src = nbr[e0 + lane];
        int dst = nbr[n_edges + e0 + lane];
        float d = dist[e0 + lane];
        float xx = d * scale;
        int i0 = (int)xx;
        i0 = max(0, min(i0, TBL - 2));
        float frac = xx - (float)i0;
        #pragma unroll 4
        for (int j = 0; j < 64; ++j) {
            const int sj = __shfl(src, j);
            const int dj = __shfl(dst, j);
            const int ij = __shfl(i0, j);
            const float fj = __shfl(frac, j);
            const float2 tv = __half22float2(tabh2[(size_t)ij * NF + lane]);
            const float filt = fmaf(fj * 256.0f, tv.y, tv.x);
            const float hv = __half2float(h16[(size_t)sj * NF + lane]);
            atomicAdd(agg + (size_t)dj * NF + lane, hv * filt);
        }
    }
    if (gw == 0) {
        for (int e = nbatch << 6; e < n_edges; ++e) {
            const int sj = nbr[e];
            const int dj = nbr[n_edges + e];
            const float d = dist[e];
            float xx = d * scale;
            int ij = (int)xx;
            ij = max(0, min(ij, TBL - 2));
            const float fj = xx - (float)ij;
            const float2 tv = __half22float2(tabh2[(size_t)ij * NF + lane]);
            const float filt = fmaf(fj * 256.0f, tv.y, tv.x);
            const float hv = __half2float(h16[(size_t)sj * NF + lane]);
            atomicAdd(agg + (size_t)dj * NF + lane, hv * filt);
        }
    }
}

// ---------------------------------------------------------------------------
// out_mlp (MFMA): out = ssp(agg@W1^T+b1)@W2^T+b2. Wave per 16-node tile.
// In-place safe: each tile's rows are read before the same wave writes them.
// ---------------------------------------------------------------------------
__global__ void __launch_bounds__(256) out_mlp_k(const float* __restrict__ agg,
                                                 const float* __restrict__ w1,
                                                 const float* __restrict__ b1,
                                                 const float* __restrict__ w2,
                                                 const float* __restrict__ b2,
                                                 float* __restrict__ out, int n_nodes) {
    __shared__ _Float16 stile[4][16][72];
    const int tid = threadIdx.x;
    const int lane = tid & 63;
    const int wid = tid >> 6;
    const int col = lane & 15;
    const int quad = lane >> 4;

    f16x8 bw1[4][2], bw2[4][2];
    float b1v[4], b2v[4];
    #pragma unroll
    for (int t = 0; t < 4; ++t) {
        #pragma unroll
        for (int kb = 0; kb < 2; ++kb) {
            bw1[t][kb] = load_wfrag(w1, 16 * t + col, kb * 32 + quad * 8);
            bw2[t][kb] = load_wfrag(w2, 16 * t + col, kb * 32 + quad * 8);
        }
        b1v[t] = b1[16 * t + col];
        b2v[t] = b2[16 * t + col];
    }

    const int ntiles = (n_nodes + 15) >> 4;
    for (int tile = blockIdx.x * 4 + wid; tile < ntiles; tile += gridDim.x * 4) {
        const int n0 = tile << 4;
        const int nr = min(n0 + col, n_nodes - 1);
        f16x8 a[2];
        #pragma unroll
        for (int kb = 0; kb < 2; ++kb)
            a[kb] = load_afrag_f32(agg + (size_t)nr * NF + kb * 32 + quad * 8);
        f32x4 acc[4];
        #pragma unroll
        for (int t = 0; t < 4; ++t) acc[t] = (f32x4){b1v[t], b1v[t], b1v[t], b1v[t]};
        #pragma unroll
        for (int t = 0; t < 4; ++t)
            #pragma unroll
            for (int kb = 0; kb < 2; ++kb)
                acc[t] = __builtin_amdgcn_mfma_f32_16x16x32_f16(a[kb], bw1[t][kb], acc[t], 0, 0, 0);
        #pragma unroll
        for (int t = 0; t < 4; ++t)
            #pragma unroll
            for (int r = 0; r < 4; ++r)
                stile[wid][quad * 4 + r][16 * t + col] = (_Float16)sspf(acc[t][r]);
        __threadfence_block();
        f16x8 a2[2];
        #pragma unroll
        for (int kb = 0; kb < 2; ++kb)
            a2[kb] = *(const f16x8*)&stile[wid][col][kb * 32 + quad * 8];
        f32x4 acc2[4];
        #pragma unroll
        for (int t = 0; t < 4; ++t) acc2[t] = (f32x4){b2v[t], b2v[t], b2v[t], b2v[t]};
        #pragma unroll
        for (int t = 0; t < 4; ++t)
            #pragma unroll
            for (int kb = 0; kb < 2; ++kb)
                acc2[t] = __builtin_amdgcn_mfma_f32_16x16x32_f16(a2[kb], bw2[t][kb], acc2[t], 0, 0, 0);
        #pragma unroll
        for (int t = 0; t < 4; ++t)
            #pragma unroll
            for (int r = 0; r < 4; ++r) {
                const int n = n0 + quad * 4 + r;
                if (n < n_nodes) out[(size_t)n * NF + 16 * t + col] = acc2[t][r];
            }
        __threadfence_block();
    }
}

extern "C" void kernel_launch(void* const* d_in, const int* in_sizes, int n_in,
                              void* d_out, int out_size, void* d_ws, size_t ws_size,
                              hipStream_t stream) {
    const int*   nbr   = (const int*)d_in[0];
    const float* dist  = (const float*)d_in[1];
    const float* x     = (const float*)d_in[2];
    const float* lin_w = (const float*)d_in[3];
    const float* lin_b = (const float*)d_in[4];
    const float* f_w1  = (const float*)d_in[5];
    const float* f_b1  = (const float*)d_in[6];
    const float* f_w2  = (const float*)d_in[7];
    const float* f_b2  = (const float*)d_in[8];
    const float* m_w1  = (const float*)d_in[9];
    const float* m_b1  = (const float*)d_in[10];
    const float* m_w2  = (const float*)d_in[11];
    const float* m_b2  = (const float*)d_in[12];

    const int n_edges = in_sizes[1];
    const int n_nodes = in_sizes[2] / NF;
    const int ngroups = (n_nodes + GRP - 1) / GRP;
    const int chk     = (n_edges + NSC - 1) / NSC;
    const int ntiles  = (n_nodes + 15) / 16;
    const int mlp_blk = (ntiles + 3) / 4;

    float* out = (float*)d_out;
    float* agg = out;   // agg lives in d_out; out_mlp runs in place

    // workspace: h16 | tabh2 | cnt | colpre | tot | gbase | payload
    char* ws = (char*)d_ws;
    size_t off = 0;
    auto alloc = [&](size_t bytes) { char* p = ws + off; off = (off + bytes + 255) & ~(size_t)255; return p; };
    __half*   h16     = (__half*)alloc((size_t)n_nodes * NF * sizeof(__half));
    __half2*  tabh2   = (__half2*)alloc((size_t)TBL * NF * sizeof(__half2));
    unsigned* cnt     = (unsigned*)alloc((size_t)NSC * ngroups * sizeof(unsigned));
    unsigned* colpre  = (unsigned*)alloc((size_t)NSC * ngroups * sizeof(unsigned));
    unsigned* tot     = (unsigned*)alloc((size_t)ngroups * sizeof(unsigned));
    unsigned* gbase   = (unsigned*)alloc((size_t)(ngroups + 1) * sizeof(unsigned));
    ull*      payload = (ull*)alloc((size_t)NSC * chk * sizeof(ull));
    const bool sort_path = (off <= ws_size) && (ngroups <= GMAX) && (n_nodes <= (1 << 17));

    build_tabh2_k<<<TBL, 64, 0, stream>>>(f_w1, f_b1, f_w2, f_b2, tabh2);
    prep_k<<<mlp_blk, 256, 0, stream>>>(x, lin_w, lin_b, h16, n_nodes);

    if (sort_path) {
        hist_k<<<NSC, 1024, 0, stream>>>(nbr + n_edges, n_edges, ngroups, chk, cnt);
        colscan_k<<<ngroups, 64, 0, stream>>>(cnt, colpre, tot, ngroups);
        base_k<<<1, 64, 0, stream>>>(tot, gbase, ngroups);
        scatter2_k<<<NSC, 1024, 0, stream>>>(nbr, dist, n_edges, ngroups, chk,
                                             colpre, gbase, payload);
        agg_k<<<ngroups, 256, 0, stream>>>(payload, gbase, h16, tabh2, agg, n_nodes);
        oflow2_k<<<ngroups, 64, 0, stream>>>(payload, gbase, h16, tabh2, agg);
    } else {
        hipMemsetAsync(agg, 0, (size_t)n_nodes * NF * sizeof(float), stream);
        edge_k<<<2048, 256, 0, stream>>>(nbr, dist, h16, tabh2, agg, n_edges);
    }
    out_mlp_k<<<mlp_blk, 256, 0, stream>>>(agg, m_w1, m_b1, m_w2, m_b2, out, n_nodes);
}